// Round 2
// baseline (1393.387 us; speedup 1.0000x reference)
//
#include <hip/hip_runtime.h>

// BatchedTrilLinear: y[n, b*64+o] = sum_{i<o} W[b,o,i]*x[n,b*64+i] + exp(W[b,o,o])*x[n,b*64+o]
// N=4096 rows, B=512 blocks, D=64. All fp32.
//
// Strategy: memory-bound (1.08 GB min traffic -> ~171us floor @6.3TB/s).
// One thread per (row, block): x-segment (256B) lives in 64 VGPRs
// (compile-time indexed only -> stays in registers), W[b] is wave-uniform
// (b derived from blockIdx only) -> compiler's uniformity analysis lowers
// wb[] loads to s_load feeding v_fmac_f32 v,s,v: zero LDS traffic.
// Triangular bound fully unrolled (2080 FMAs) -> ~57us VALU, under the
// memory floor.
//
// __launch_bounds__(256,2): do NOT force a 128-VGPR cap (256,4) — est.
// VGPR use ~90-110 and a forced spill to scratch across 2M threads would
// dwarf any occupancy gain. 16 independent dwordx4 loads/thread give
// enough ILP to latency-hide at 2-4 waves/EU.

#define D 64
#define NBLK 512
#define ROWLEN (NBLK * D)   // 32768 floats per row

__global__ __launch_bounds__(256, 2)
void btl_kernel(const float* __restrict__ x,
                const float* __restrict__ w,
                float* __restrict__ y)
{
    const int bid = blockIdx.x;
    const int b   = bid >> 4;                         // block 0..511 (wave-uniform)
    const int n   = ((bid & 15) << 8) + threadIdx.x;  // row 0..4095

    const float* __restrict__ xr = x + (size_t)n * ROWLEN + b * D;
    float*       __restrict__ yr = y + (size_t)n * ROWLEN + b * D;
    const float* __restrict__ wb = w + (size_t)b * (D * D);

    // Load this thread's 64-float x segment into registers (16 x float4).
    float xv[D];
#pragma unroll
    for (int c = 0; c < D / 4; ++c) {
        const float4 v = *reinterpret_cast<const float4*>(xr + 4 * c);
        xv[4 * c + 0] = v.x;
        xv[4 * c + 1] = v.y;
        xv[4 * c + 2] = v.z;
        xv[4 * c + 3] = v.w;
    }

    // Compute 64 outputs; o and i are compile-time constants after unroll,
    // so xv[] stays in VGPRs and wb[] offsets fold into s_load immediates.
#pragma unroll
    for (int og = 0; og < D / 4; ++og) {
        float acc[4];
#pragma unroll
        for (int j = 0; j < 4; ++j) {
            const int o = 4 * og + j;
            // diagonal: exp(W[o][o]) * x[o]
            float a = xv[o] * __expf(wb[o * D + o]);
            // strictly-lower triangle
#pragma unroll
            for (int i = 0; i < o; ++i) {
                a = fmaf(wb[o * D + i], xv[i], a);
            }
            acc[j] = a;
        }
        float4 out;
        out.x = acc[0]; out.y = acc[1]; out.z = acc[2]; out.w = acc[3];
        *reinterpret_cast<float4*>(yr + 4 * og) = out;
    }
}

extern "C" void kernel_launch(void* const* d_in, const int* in_sizes, int n_in,
                              void* d_out, int out_size, void* d_ws, size_t ws_size,
                              hipStream_t stream)
{
    const float* x = (const float*)d_in[0];   // [4096, 32768] fp32
    const float* w = (const float*)d_in[1];   // [512, 64, 64] fp32
    float* y = (float*)d_out;                 // [4096, 32768] fp32

    const int n_rows = in_sizes[0] / ROWLEN;        // 4096
    const int grid   = (n_rows / 256) * NBLK;       // 16 * 512 = 8192
    btl_kernel<<<grid, 256, 0, stream>>>(x, w, y);
}

// Round 4
// 1306.552 us; speedup vs baseline: 1.0665x; 1.0665x over previous
//
#include <hip/hip_runtime.h>

// BatchedTrilLinear: y[n, b*64+o] = sum_{i<o} W[b,o,i]*x[n,b*64+i] + exp(W[b,o,o])*x[n,b*64+o]
// N=4096 rows, B=512 blocks, D=64, fp32.
//
// Round-2 lessons (rocprof): FETCH was ideal but WRITE had 3x amplification
// (partial-line writes interleaved with compute -> L2 evicts dirty partials),
// and per-instruction 64-line fan-out (lane stride 128KiB) capped BW at 2.9TB/s
// with VALUBusy 12%.
//
// This version: workgroup = 64 rows x 4 blocks tile.
//  - x staged via LDS with fully coalesced loads (each wave reads 1KiB contiguous)
//  - wave w owns block b0+w (readfirstlane -> W loads stay scalar s_load,
//    FMAs are v_fmac v,s,v — proven to work in round 2 at 12% VALUBusy)
//  - LDS float4-index XOR swizzle (cc ^ (r&7)): all four access patterns hit
//    8 lanes/bank-group = the wave64 minimum, zero conflicts
//  - outputs written back to the thread-PRIVATE LDS segment (no extra barrier),
//    then cooperative coalesced store-out: 16 full 64B lines per wave instr,
//    write amplification eliminated.

#define D 64
#define NBLK 512
#define ROWLEN (NBLK * D)     // 32768 floats per row
#define ROWF4 (ROWLEN / 4)    // 8192 float4 per row

__global__ __launch_bounds__(256)
void btl_kernel(const float* __restrict__ x,
                const float* __restrict__ w,
                float* __restrict__ y)
{
    // 64 rows x 64 float4 (= 4 blocks x 64 floats) = 64 KiB
    __shared__ float4 tile[64 * 64];

    const int tid = threadIdx.x;
    const int rt  = blockIdx.x >> 7;     // row tile 0..63
    const int bt  = blockIdx.x & 127;    // block tile 0..127 (fast-varying:
                                         // same bt -> same XCD (128%8==0) -> W[b] L2-resident)
    const int n0  = rt << 6;

    // ---- stage x tile: 16 iters, each wave loads 1KiB contiguous ----
    const float4* __restrict__ xg =
        reinterpret_cast<const float4*>(x) + (size_t)n0 * ROWF4 + bt * 64;
#pragma unroll
    for (int k = 0; k < 16; ++k) {
        const int f  = (k << 8) + tid;   // float4 index within tile, 0..4095
        const int r  = f >> 6;           // row 0..63 (wave-uniform per iter)
        const int cc = f & 63;           // float4 within row segment
        tile[(r << 6) + (cc ^ (r & 7))] = xg[(size_t)r * ROWF4 + cc];
    }
    __syncthreads();

    // ---- compute: wave w handles block bt*4+w, lane r handles row n0+r ----
    const int wv = __builtin_amdgcn_readfirstlane(tid >> 6); // 0..3, forced SGPR
    const int r  = tid & 63;
    const int b  = (bt << 2) + wv;
    const float* __restrict__ wb = w + (size_t)b * (D * D);

    const int base = r << 6;
    const int s    = r & 7;

    // read own 64-float segment from LDS into registers (16 x ds_read_b128)
    float xv[D];
#pragma unroll
    for (int c = 0; c < 16; ++c) {
        const float4 v = tile[base + (((wv << 4) + c) ^ s)];
        xv[4 * c + 0] = v.x;
        xv[4 * c + 1] = v.y;
        xv[4 * c + 2] = v.z;
        xv[4 * c + 3] = v.w;
    }

    // triangular compute, fully unrolled; W via scalar loads (wb uniform).
    // Output float4s overwrite this thread's own LDS segment (sole reader),
    // and all reads above completed in program order -> no barrier needed.
#pragma unroll
    for (int og = 0; og < 16; ++og) {
        float acc[4];
#pragma unroll
        for (int j = 0; j < 4; ++j) {
            const int o = 4 * og + j;
            float a = xv[o] * __expf(wb[o * (D + 1)]);   // diag: exp(W[o][o])
#pragma unroll
            for (int i = 0; i < o; ++i) {
                a = fmaf(wb[(o << 6) + i], xv[i], a);
            }
            acc[j] = a;
        }
        float4 out;
        out.x = acc[0]; out.y = acc[1]; out.z = acc[2]; out.w = acc[3];
        tile[base + (((wv << 4) + og) ^ s)] = out;
    }
    __syncthreads();

    // ---- store out: same coalesced pattern, 16 full lines per wave instr ----
    float4* __restrict__ yg =
        reinterpret_cast<float4*>(y) + (size_t)n0 * ROWF4 + bt * 64;
#pragma unroll
    for (int k = 0; k < 16; ++k) {
        const int f  = (k << 8) + tid;
        const int r2 = f >> 6;
        const int cc = f & 63;
        yg[(size_t)r2 * ROWF4 + cc] = tile[(r2 << 6) + (cc ^ (r2 & 7))];
    }
}

extern "C" void kernel_launch(void* const* d_in, const int* in_sizes, int n_in,
                              void* d_out, int out_size, void* d_ws, size_t ws_size,
                              hipStream_t stream)
{
    const float* x = (const float*)d_in[0];   // [4096, 32768] fp32
    const float* w = (const float*)d_in[1];   // [512, 64, 64] fp32
    float* y = (float*)d_out;                 // [4096, 32768] fp32

    const int n_rows = in_sizes[0] / ROWLEN;             // 4096
    const int grid   = (n_rows / 64) * (NBLK / 4);       // 64 * 128 = 8192
    btl_kernel<<<grid, 256, 0, stream>>>(x, w, y);
}

// Round 5
// 906.968 us; speedup vs baseline: 1.5363x; 1.4406x over previous
//
#include <hip/hip_runtime.h>

// BatchedTrilLinear: y[n, b*64+o] = sum_{i<o} W[b,o,i]*x[n,b*64+i] + exp(W[b,o,o])*x[n,b*64+o]
// N=4096, B=512, D=64, fp32.
//
// History (rocprof-driven):
//  R2: per-lane global r/w, W via s_load: 765us. FETCH ideal, WRITE 3x amplified,
//      VALUBusy 12%.
//  R4: LDS-staged r/w fixed WRITE (exactly 512MiB) but dur only 703us @1.25TB/s
//      -> memory was NOT the binding constraint. Real limiter (common to both):
//      ~2080 scalar s_load_dword of W per wave, serialized through the 16KB
//      scalar K$ (4 different b per wg -> thrash), batch-load/lgkmcnt/consume
//      chains that neither occupancy nor ILP can hide.
//  R5 (this): W delivered via LDS BROADCAST instead of s_load.
//      wg = 256 rows x 1 block (all 4 waves share b). LDS = x-tile 64KB
//      (XOR-swizzled, conflict-free) + W[b] 16KB = exactly 80KB -> 2 wg/CU.
//      Diagonal replaced in-LDS by exp(diag) once (64 v_exp per WG, not per
//      thread). Triangle reads W as uniform float4 ds_reads (broadcast ==
//      conflict-free), ~544 b128/wave hidden under 4160cy of FMA. Outputs
//      overwrite the thread-private x row slots; cooperative full-line
//      store-out (proven ideal in R4).

#define D 64
#define NBLK 512
#define ROWF4 8192          // 32768 floats per x/y row = 8192 float4

__global__ __launch_bounds__(256)
void btl_kernel(const float* __restrict__ x,
                const float* __restrict__ w,
                float* __restrict__ y)
{
    // x tile: 256 rows x 16 float4 (64KB). Slot (r, c) holds global f4
    // (r, c ^ (r&15)) — XOR involution; reads/writes of global (r,i) use
    // slot (r, i^(r&15)). W tile: 16KB square.
    __shared__ float4 xt[256 * 16];
    __shared__ float4 wt[64 * 16];

    const int tid = threadIdx.x;
    const int b   = blockIdx.x >> 4;     // block 0..511 (wave-uniform)
    const int rt  = blockIdx.x & 15;     // row tile 0..15
    const int n0  = rt << 8;             // first of 256 rows

    const float4* __restrict__ xg = reinterpret_cast<const float4*>(x)
                                    + (size_t)n0 * ROWF4 + b * 16;
    const float4* __restrict__ wg = reinterpret_cast<const float4*>(w)
                                    + (size_t)b * 1024;

    // ---- stage x (swizzled dest, coalesced source) + W (linear) ----
#pragma unroll
    for (int k = 0; k < 16; ++k) {
        const int f = (k << 8) + tid;
        const int r = f >> 4;            // 0..255
        const int c = f & 15;
        xt[(r << 4) + (c ^ (r & 15))] = xg[(size_t)r * ROWF4 + c];
    }
#pragma unroll
    for (int k = 0; k < 4; ++k) {
        const int f = (k << 8) + tid;
        wt[f] = wg[f];
    }
    __syncthreads();

    // ---- replace W diagonal with exp(diagonal), in LDS (stride 65 -> 2-way, free)
    if (tid < 64) {
        float* wf = reinterpret_cast<float*>(wt);
        wf[tid * 65] = __expf(wf[tid * 65]);
    }
    __syncthreads();

    // ---- compute: lane -> row; W rows read as uniform (broadcast) float4 ----
    const int r    = tid;                // rows 0..255, wave wv owns 64wv..64wv+63
    const int s    = r & 15;
    const int base = r << 4;

    float xv[D];
#pragma unroll
    for (int c = 0; c < 16; ++c) {
        const float4 v = xt[base + (c ^ s)];
        xv[4 * c + 0] = v.x;
        xv[4 * c + 1] = v.y;
        xv[4 * c + 2] = v.z;
        xv[4 * c + 3] = v.w;
    }

#pragma unroll
    for (int og = 0; og < 16; ++og) {
        float acc[4];
#pragma unroll
        for (int j = 0; j < 4; ++j) {
            const int o   = (og << 2) + j;
            const int q   = o >> 2;      // f4 chunk containing the diagonal
            const int rem = o & 3;       // position of diag within that chunk
            // chunk q: first `rem` elements are off-diag (i=4q..o-1),
            // element `rem` is exp(W[o][o]).
            const float4 t  = wt[(o << 4) + q];
            const float* tf = reinterpret_cast<const float*>(&t);
            float a = xv[o] * tf[rem];
#pragma unroll
            for (int jj = 0; jj < 3; ++jj)
                if (jj < rem) a = fmaf(tf[jj], xv[(q << 2) + jj], a);
#pragma unroll
            for (int c4 = 0; c4 < 15; ++c4) {
                if (c4 < q) {
                    const float4 wv4 = wt[(o << 4) + c4];
                    const float* wf4 = reinterpret_cast<const float*>(&wv4);
                    a = fmaf(wf4[0], xv[(c4 << 2) + 0], a);
                    a = fmaf(wf4[1], xv[(c4 << 2) + 1], a);
                    a = fmaf(wf4[2], xv[(c4 << 2) + 2], a);
                    a = fmaf(wf4[3], xv[(c4 << 2) + 3], a);
                }
            }
            acc[j] = a;
        }
        // overwrite this thread's own row slot (sole reader/writer, no barrier)
        float4 out;
        out.x = acc[0]; out.y = acc[1]; out.z = acc[2]; out.w = acc[3];
        xt[base + (og ^ s)] = out;
    }
    __syncthreads();

    // ---- cooperative store-out: 16 full 64B lines per wave instruction ----
    float4* __restrict__ yg = reinterpret_cast<float4*>(y)
                              + (size_t)n0 * ROWF4 + b * 16;
#pragma unroll
    for (int k = 0; k < 16; ++k) {
        const int f  = (k << 8) + tid;
        const int r2 = f >> 4;
        const int c  = f & 15;
        yg[(size_t)r2 * ROWF4 + c] = xt[(r2 << 4) + (c ^ (r2 & 15))];
    }
}

extern "C" void kernel_launch(void* const* d_in, const int* in_sizes, int n_in,
                              void* d_out, int out_size, void* d_ws, size_t ws_size,
                              hipStream_t stream)
{
    const float* x = (const float*)d_in[0];   // [4096, 32768] fp32
    const float* w = (const float*)d_in[1];   // [512, 64, 64] fp32
    float* y = (float*)d_out;                 // [4096, 32768] fp32

    const int n_rows = in_sizes[0] / (NBLK * D);   // 4096
    const int grid   = NBLK * (n_rows / 256);      // 512 * 16 = 8192
    btl_kernel<<<grid, 256, 0, stream>>>(x, w, y);
}